// Round 1
// baseline (4500.612 us; speedup 1.0000x reference)
//
#include <hip/hip_runtime.h>
#include <hip/hip_bf16.h>

// Scatter-mean: out[n, :] = sum_{e: index[e]==n} msg[e, :] / max(count[n], 1)
// E = 2,000,000 edges, D = 128, N = 100,000 segments.
//
// Round 1 strategy: atomic scatter-add baseline.
//   kernel 1: per-edge atomicAdd of the 128-float row into out[index[e]], plus
//             one count atomic per edge.
//   kernel 2: normalize by max(count,1).
// Expected bottleneck: 256M fp32 global atomics (TCC-bound), not HBM.

#define D 128
#define D4 (D / 4)  // 32 float4 per row

__global__ __launch_bounds__(256) void scatter_add_kernel(
    const float* __restrict__ msg, const int* __restrict__ index,
    float* __restrict__ out, float* __restrict__ counts, int E) {
    // 32 threads per edge; each thread handles one float4 (4 consecutive floats).
    long long gid = (long long)blockIdx.x * blockDim.x + threadIdx.x;
    int edge = (int)(gid >> 5);
    int lane = (int)(gid & 31);
    if (edge >= E) return;

    int seg = index[edge];

    const float4* msg4 = (const float4*)msg;
    float4 v = msg4[(long long)edge * D4 + lane];

    float* o = out + (long long)seg * D + lane * 4;
    atomicAdd(o + 0, v.x);
    atomicAdd(o + 1, v.y);
    atomicAdd(o + 2, v.z);
    atomicAdd(o + 3, v.w);

    if (lane == 0) {
        atomicAdd(counts + seg, 1.0f);
    }
}

__global__ __launch_bounds__(256) void normalize_kernel(
    float* __restrict__ out, const float* __restrict__ counts, int N) {
    // 32 threads per segment row; each thread one float4.
    long long gid = (long long)blockIdx.x * blockDim.x + threadIdx.x;
    int n = (int)(gid >> 5);
    int lane = (int)(gid & 31);
    if (n >= N) return;

    float c = counts[n];
    c = fmaxf(c, 1.0f);

    float4* out4 = (float4*)out;
    long long p = (long long)n * D4 + lane;
    float4 v = out4[p];
    v.x /= c;
    v.y /= c;
    v.z /= c;
    v.w /= c;
    out4[p] = v;
}

extern "C" void kernel_launch(void* const* d_in, const int* in_sizes, int n_in,
                              void* d_out, int out_size, void* d_ws, size_t ws_size,
                              hipStream_t stream) {
    const float* msg   = (const float*)d_in[0];
    const int*   index = (const int*)d_in[1];
    // d_in[2] (t) unused by the reference; d_in[3] (dim_size) derived from out_size.
    float* out = (float*)d_out;

    int E = in_sizes[1];          // 2,000,000
    int N = out_size / D;         // 100,000

    float* counts = (float*)d_ws; // N floats = 400 KB scratch

    // Harness poisons d_out / d_ws with 0xAA before every timed launch.
    hipMemsetAsync(out, 0, (size_t)out_size * sizeof(float), stream);
    hipMemsetAsync(counts, 0, (size_t)N * sizeof(float), stream);

    {
        long long total = (long long)E * 32;
        int block = 256;
        long long grid = (total + block - 1) / block;
        scatter_add_kernel<<<(dim3)(unsigned)grid, block, 0, stream>>>(
            msg, index, out, counts, E);
    }
    {
        long long total = (long long)N * 32;
        int block = 256;
        long long grid = (total + block - 1) / block;
        normalize_kernel<<<(dim3)(unsigned)grid, block, 0, stream>>>(out, counts, N);
    }
}